// Round 1
// 466.355 us; speedup vs baseline: 1.0929x; 1.0929x over previous
//
#include <hip/hip_runtime.h>
#include <stdint.h>

#define NN   8192
#define DIN  512
#define DOUT 512
#define ALPHA 0.2f

typedef float          floatx4  __attribute__((ext_vector_type(4)));
typedef float          floatx2  __attribute__((ext_vector_type(2)));
typedef short          shortx8  __attribute__((ext_vector_type(8)));
typedef unsigned short ushortx4 __attribute__((ext_vector_type(4)));
typedef int            intx2    __attribute__((ext_vector_type(2)));
typedef int            intx4    __attribute__((ext_vector_type(4)));
typedef unsigned       uintx2   __attribute__((ext_vector_type(2)));

__device__ inline unsigned short f2bf(float x) {
    union { float f; unsigned u; } v; v.f = x;
    return (unsigned short)((v.u + 0x7FFFu + ((v.u >> 16) & 1u)) >> 16);
}
__device__ inline unsigned encf(float x) {
    union { float f; unsigned u; } v; v.f = x;
    return (v.u & 0x80000000u) ? ~v.u : (v.u | 0x80000000u);
}
__device__ inline float decf(unsigned e) {
    union { float f; unsigned u; } v;
    v.u = (e & 0x80000000u) ? (e & 0x7FFFFFFFu) : ~e;
    return v.f;
}
__device__ inline float lrelu(float x) { return fmaxf(x, ALPHA * x); }

// ---------------------------------------------------------------------------
// Kernel T: WT[n][k] = bf16(W[k][n])   (512x512)
// ---------------------------------------------------------------------------
__global__ __launch_bounds__(256) void transpose_w(const float* __restrict__ W,
                                                   unsigned short* __restrict__ WT) {
    __shared__ float tile[32][33];
    const int t = threadIdx.x;
    const int x = t & 31, y = t >> 5;
    const int tr = (blockIdx.x >> 4) * 32, tc = (blockIdx.x & 15) * 32;
#pragma unroll
    for (int i = 0; i < 4; i++) {
        int r = y + i * 8;
        tile[r][x] = W[(size_t)(tr + r) * DOUT + tc + x];
    }
    __syncthreads();
#pragma unroll
    for (int i = 0; i < 4; i++) {
        int r = y + i * 8;
        WT[(size_t)(tc + r) * DIN + tr + x] = f2bf(tile[x][r]);
    }
}

// ---------------------------------------------------------------------------
// Kernel A: Wh = h @ W (bf16 MFMA). 512 blocks x 16 rows, 4 waves (16r x 128c).
// Writes Wh in k-major fragment-tiled layout WhTt[tile_k][tile_n][512],
// f1 = Wh@a1, f2 = Wh@a2, max(f2).  (unchanged this round)
// ---------------------------------------------------------------------------
__global__ __launch_bounds__(256) void gemm_wh(
    const float* __restrict__ h, const unsigned short* __restrict__ WT,
    const float* __restrict__ a, unsigned short* __restrict__ WhTt,
    float* __restrict__ f1, float* __restrict__ f2, unsigned* __restrict__ Menc)
{
    __shared__ float f1s[4][16], f2s[4][16];
    const int t = threadIdx.x;
    const int w = t >> 6, lane = t & 63, l15 = lane & 15, q = lane >> 4;
    const int r0 = blockIdx.x * 16;
    const int wc0 = w * 128;

    floatx4 acc[8];
    const floatx4 z4 = {0.f, 0.f, 0.f, 0.f};
#pragma unroll
    for (int j = 0; j < 8; j++) acc[j] = z4;

    const float* hp = &h[(size_t)(r0 + l15) * DIN + q * 8];
    const unsigned short* bp = &WT[(size_t)(wc0 + l15) * DIN + q * 8];

    floatx4 hA[2][2];
    shortx8 bB[2][8];
    hA[0][0] = *(const floatx4*)hp;
    hA[0][1] = *(const floatx4*)(hp + 4);
#pragma unroll
    for (int nt = 0; nt < 8; nt++)
        bB[0][nt] = *(const shortx8*)(bp + (size_t)nt * 16 * DIN);

#pragma unroll 2
    for (int it = 0; it < 16; ++it) {
        const int c = it & 1, n = c ^ 1;
        const int kn = ((it + 1) & 15) * 32;
        hA[n][0] = *(const floatx4*)(hp + kn);
        hA[n][1] = *(const floatx4*)(hp + kn + 4);
#pragma unroll
        for (int nt = 0; nt < 8; nt++)
            bB[n][nt] = *(const shortx8*)(bp + (size_t)nt * 16 * DIN + kn);

        shortx8 af;
#pragma unroll
        for (int j = 0; j < 8; j++)
            af[j] = (short)f2bf(hA[c][j >> 2][j & 3]);
#pragma unroll
        for (int nt = 0; nt < 8; nt++)
            acc[nt] = __builtin_amdgcn_mfma_f32_16x16x32_bf16(af, bB[c][nt], acc[nt], 0, 0, 0);
    }

    float a1v[8], a2v[8];
#pragma unroll
    for (int nt = 0; nt < 8; nt++) {
        int col = wc0 + nt * 16 + l15;
        a1v[nt] = a[col];
        a2v[nt] = a[DOUT + col];
    }
    {
        const int kk0 = r0 + q * 4;
        const int tile_k = kk0 >> 5;
        const int qq = (kk0 >> 3) & 3;
        const int j0 = kk0 & 7;
#pragma unroll
        for (int nt = 0; nt < 8; nt++) {
            const int tile_n = w * 8 + nt;
            ushortx4 pk;
#pragma unroll
            for (int reg = 0; reg < 4; reg++) pk[reg] = f2bf(acc[nt][reg]);
            *(ushortx4*)&WhTt[(((size_t)tile_k * 32 + tile_n) << 9) + qq * 128 + l15 * 8 + j0] = pk;
        }
    }
    float s1a[4], s2a[4];
#pragma unroll
    for (int reg = 0; reg < 4; reg++) {
        float s1 = 0.f, s2 = 0.f;
#pragma unroll
        for (int nt = 0; nt < 8; nt++) {
            s1 += acc[nt][reg] * a1v[nt];
            s2 += acc[nt][reg] * a2v[nt];
        }
        s1 += __shfl_xor(s1, 1, 64); s2 += __shfl_xor(s2, 1, 64);
        s1 += __shfl_xor(s1, 2, 64); s2 += __shfl_xor(s2, 2, 64);
        s1 += __shfl_xor(s1, 4, 64); s2 += __shfl_xor(s2, 4, 64);
        s1 += __shfl_xor(s1, 8, 64); s2 += __shfl_xor(s2, 8, 64);
        s1a[reg] = s1; s2a[reg] = s2;
    }
    if (l15 == 0) {
#pragma unroll
        for (int reg = 0; reg < 4; reg++) {
            f1s[w][q * 4 + reg] = s1a[reg];
            f2s[w][q * 4 + reg] = s2a[reg];
        }
    }
    __syncthreads();
    if (t < 16) {
        float v1 = f1s[0][t] + f1s[1][t] + f1s[2][t] + f1s[3][t];
        float v2 = f2s[0][t] + f2s[1][t] + f2s[2][t] + f2s[3][t];
        f1[r0 + t] = v1;
        f2[r0 + t] = v2;
        float mx = v2;
        mx = fmaxf(mx, __shfl_xor(mx, 1, 64));
        mx = fmaxf(mx, __shfl_xor(mx, 2, 64));
        mx = fmaxf(mx, __shfl_xor(mx, 4, 64));
        mx = fmaxf(mx, __shfl_xor(mx, 8, 64));
        if (t == 0) atomicMax(Menc, encf(mx));
    }
}

// ---------------------------------------------------------------------------
// Kernel 2: GAT aggregation. R5: 64 rows/block x 256 cols/block (col-split),
// halving the WhTt re-stream from 2 GB -> 1 GB (theory: the kernel is bound
// by the L3 WhTt stream at ~12 TB/s, not by any counted pipe).
// Grid = 256 blocks x 1024 threads = 1 block/CU. Block = (rg, chalf):
// rows rg*64..+64, cols chalf*256..+256, k = 8192.
// XCD-paired decode: bid&7 = XCD (HW round-robin), rg = f(XCD) so both
// col-halves of a row-group are co-resident on one XCD -> the duplicated
// adj slice read hits L2 instead of HBM.
// Wave = (ks = w>>3 k-half of 4096, cw = w&7 col-group of 32); 128 iters of
// 32k. p ownership: prow = u>>3 (64 rows), pk = u&7 (4 k each): 8 lanes/row
// read 128 B adj contiguously (nontemporal). 4 exps/thread/iter (exp work
// x2 vs R4 -- duplicated across col-halves, ~10us VALU, overlapped).
// A-frags: 4 row-groups x 16 read from padded pbuf (stride 40, <=2-way).
// B: 2x 1KB tiles/iter/wave (half of R4), reg double-buffered, all waves
// walk tile_k in the same order. k-halves merged in-block via red2.
// acc[4][2] = 32 VGPR; est total ~100 < 128 cap (16 waves/CU).
// ---------------------------------------------------------------------------
__global__ __launch_bounds__(1024, 4) void gat_agg(
    const int* __restrict__ adj, const unsigned short* __restrict__ WhTt,
    const float* __restrict__ f1, const float* __restrict__ f2,
    const unsigned* __restrict__ Menc, float* __restrict__ out)
{
    __shared__ __align__(16) unsigned short pbuf[2][2][64 * 40]; // 20 KB
    __shared__ float red2[64][260];                              // 65 KB
    __shared__ float lsp[2][8][64];
    __shared__ float linv[64];

    const int t = threadIdx.x;
    const int w = t >> 6, lane = t & 63, l15 = lane & 15, q = lane >> 4;
    const int ks = w >> 3, cw = w & 7;
    const int u = (w & 7) * 64 + lane;        // 0..511 within ks-group
    const int prow = u >> 3, pk = u & 7;      // p ownership: row, k-quad

    // XCD-paired block decode (bid%8 -> XCD assumed; perf-only if wrong)
    const int xcd = blockIdx.x & 7, sidx = blockIdx.x >> 3;
    const int chalf = sidx & 1;
    const int rgid = xcd * 16 + (sidx >> 1);  // 0..127
    const int r0 = rgid * 64;
    const int cb = chalf * 256;

    const float M = decf(*Menc);
    const float f1v = f1[r0 + prow];
    const float mi = lrelu(f1v + M);

    floatx4 acc[4][2];
    const floatx4 z4 = {0.f, 0.f, 0.f, 0.f};
#pragma unroll
    for (int i = 0; i < 4; i++)
#pragma unroll
        for (int j = 0; j < 2; j++) acc[i][j] = z4;
    float ls = 0.f;

    // B base: tile_k = ks*128 + it, tile_n = chalf*16 + cw*2 + nt
    const unsigned short* bpp = WhTt
        + (((size_t)(ks * 128) * 32 + chalf * 16 + cw * 2) << 9) + lane * 8;
    const int* arp = adj + (size_t)(r0 + prow) * NN + ks * 4096 + pk * 4;
    const float* fpp = f2 + ks * 4096 + pk * 4;

    intx4   adjr[2];
    floatx4 ffr[2];
    shortx8 breg[2][2];

    // prologue: inputs for tiles 0,1; p(0) -> pbuf[ks][0]; B(0)
    adjr[0] = __builtin_nontemporal_load((const intx4*)arp);
    adjr[1] = __builtin_nontemporal_load((const intx4*)(arp + 32));
    ffr[0] = *(const floatx4*)fpp;
    ffr[1] = *(const floatx4*)(fpp + 32);
    {
        float p0 = __expf(lrelu(f1v + ffr[0][0]) - mi);
        float p1 = __expf(lrelu(f1v + ffr[0][1]) - mi);
        float p2 = __expf(lrelu(f1v + ffr[0][2]) - mi);
        float p3 = __expf(lrelu(f1v + ffr[0][3]) - mi);
        p0 = (adjr[0][0] > 0) ? p0 : 0.f;
        p1 = (adjr[0][1] > 0) ? p1 : 0.f;
        p2 = (adjr[0][2] > 0) ? p2 : 0.f;
        p3 = (adjr[0][3] > 0) ? p3 : 0.f;
        ls += (p0 + p1) + (p2 + p3);
        uintx2 dd;
        dd[0] = __builtin_amdgcn_perm(__float_as_uint(p1), __float_as_uint(p0), 0x07060302u);
        dd[1] = __builtin_amdgcn_perm(__float_as_uint(p3), __float_as_uint(p2), 0x07060302u);
        *(uintx2*)&pbuf[ks][0][prow * 40 + pk * 4] = dd;
    }
    breg[0][0] = *(const shortx8*)bpp;
    breg[0][1] = *(const shortx8*)(bpp + 512);
    __syncthreads();

#pragma unroll 2
    for (int it = 0; it < 128; ++it) {
        const int c = it & 1, n = c ^ 1;
        const int nx = (it + 1) & 127;         // wraps harmlessly on last iter
        const int nx2 = (it + 2) & 127;

        // B(it+1) -> breg[n]
        breg[n][0] = *(const shortx8*)(bpp + (size_t)nx * 16384);
        breg[n][1] = *(const shortx8*)(bpp + (size_t)nx * 16384 + 512);
        // inputs for it+2 -> slot c (slot c's tile-it inputs already consumed)
        const intx4   ad_n = adjr[n];
        const floatx4 ff_n = ffr[n];
        adjr[c] = __builtin_nontemporal_load((const intx4*)(arp + nx2 * 32));
        ffr[c] = *(const floatx4*)(fpp + nx2 * 32);

        // p(it+1) -> pbuf[ks][n]  (skip wrapped p(128) at it=127)
        if (it < 127) {
            float p0 = __expf(lrelu(f1v + ff_n[0]) - mi);
            float p1 = __expf(lrelu(f1v + ff_n[1]) - mi);
            float p2 = __expf(lrelu(f1v + ff_n[2]) - mi);
            float p3 = __expf(lrelu(f1v + ff_n[3]) - mi);
            p0 = (ad_n[0] > 0) ? p0 : 0.f;
            p1 = (ad_n[1] > 0) ? p1 : 0.f;
            p2 = (ad_n[2] > 0) ? p2 : 0.f;
            p3 = (ad_n[3] > 0) ? p3 : 0.f;
            ls += (p0 + p1) + (p2 + p3);
            uintx2 dd;
            dd[0] = __builtin_amdgcn_perm(__float_as_uint(p1), __float_as_uint(p0), 0x07060302u);
            dd[1] = __builtin_amdgcn_perm(__float_as_uint(p3), __float_as_uint(p2), 0x07060302u);
            *(uintx2*)&pbuf[ks][n][prow * 40 + pk * 4] = dd;
        }

        // A-frags from pbuf[ks][c] (p(it), 4 row-groups); MFMA with breg[c]
        const shortx8 af0 = *(const shortx8*)&pbuf[ks][c][(l15) * 40 + q * 8];
        const shortx8 af1 = *(const shortx8*)&pbuf[ks][c][(16 + l15) * 40 + q * 8];
        const shortx8 af2 = *(const shortx8*)&pbuf[ks][c][(32 + l15) * 40 + q * 8];
        const shortx8 af3 = *(const shortx8*)&pbuf[ks][c][(48 + l15) * 40 + q * 8];
#pragma unroll
        for (int nt = 0; nt < 2; nt++) {
            acc[0][nt] = __builtin_amdgcn_mfma_f32_16x16x32_bf16(af0, breg[c][nt], acc[0][nt], 0, 0, 0);
            acc[1][nt] = __builtin_amdgcn_mfma_f32_16x16x32_bf16(af1, breg[c][nt], acc[1][nt], 0, 0, 0);
            acc[2][nt] = __builtin_amdgcn_mfma_f32_16x16x32_bf16(af2, breg[c][nt], acc[2][nt], 0, 0, 0);
            acc[3][nt] = __builtin_amdgcn_mfma_f32_16x16x32_bf16(af3, breg[c][nt], acc[3][nt], 0, 0, 0);
        }
        __syncthreads();
    }

    // lsum merge: unique slot per thread, then 64 threads total the rows
    lsp[ks][pk][prow] = ls;
    __syncthreads();
    if (t < 64) {
        float sden = 0.f;
#pragma unroll
        for (int g = 0; g < 2; g++)
#pragma unroll
            for (int kc = 0; kc < 8; kc++) sden += lsp[g][kc][t];
        linv[t] = 1.f / sden;
    }
    // in-block k-half merge: ks=1 parks acc in red2 (runs alongside linv calc)
    if (ks == 1) {
#pragma unroll
        for (int mt = 0; mt < 4; mt++)
#pragma unroll
            for (int nt = 0; nt < 2; nt++) {
                const int col = cw * 32 + nt * 16 + l15;
#pragma unroll
                for (int reg = 0; reg < 4; reg++)
                    red2[mt * 16 + q * 4 + reg][col] = acc[mt][nt][reg];
            }
    }
    __syncthreads();
    if (ks == 0) {
#pragma unroll
        for (int mt = 0; mt < 4; mt++)
#pragma unroll
            for (int nt = 0; nt < 2; nt++) {
                const int col = cw * 32 + nt * 16 + l15;
#pragma unroll
                for (int reg = 0; reg < 4; reg++) {
                    const int row = mt * 16 + q * 4 + reg;
                    float v = (acc[mt][nt][reg] + red2[row][col]) * linv[row];
                    v = (v > 0.f) ? v : (__expf(v) - 1.f);
                    out[(size_t)(r0 + row) * DOUT + cb + col] = v;
                }
            }
    }
}

// ---------------------------------------------------------------------------
extern "C" void kernel_launch(void* const* d_in, const int* in_sizes, int n_in,
                              void* d_out, int out_size, void* d_ws, size_t ws_size,
                              hipStream_t stream) {
    const float* h   = (const float*)d_in[0];
    const int*   adj = (const int*)d_in[1];
    const float* W   = (const float*)d_in[2];
    const float* a   = (const float*)d_in[3];
    float* out = (float*)d_out;

    char* ws = (char*)d_ws;
    unsigned short* WT    = (unsigned short*)ws;                  // 512 KB
    unsigned short* WhTt  = (unsigned short*)(ws + 524288);       // 8 MB (tiled)
    float*          f1    = (float*)(ws + 8912896);               // 32 KB
    float*          f2    = (float*)(ws + 8945664);               // 32 KB
    unsigned*       Menc  = (unsigned*)(ws + 8978432);            // 4 B

    hipMemsetAsync(Menc, 0, 4, stream);
    transpose_w<<<256, 256, 0, stream>>>(W, WT);
    gemm_wh<<<512, 256, 0, stream>>>(h, WT, a, WhTt, f1, f2, Menc);
    gat_agg<<<256, 1024, 0, stream>>>(adj, WhTt, f1, f2, Menc, out);
}